// Round 10
// baseline (317.270 us; speedup 1.0000x reference)
//
#include <hip/hip_runtime.h>
#include <math.h>

typedef __bf16 bf16;
typedef __bf16 bf16x4 __attribute__((ext_vector_type(4)));
typedef __bf16 bf16x8 __attribute__((ext_vector_type(8)));
typedef float f32x4 __attribute__((ext_vector_type(4)));

#define MODE_QKV    0
#define MODE_SCORES 1
#define MODE_PV     2

__device__ inline void gload_lds16(const bf16* g, bf16* l) {
    __builtin_amdgcn_global_load_lds(
        (const __attribute__((address_space(1))) void*)g,
        (__attribute__((address_space(3))) void*)l, 16, 0, 0);
}

// ds_read_b128 with a compile-time immediate offset. asm-opaque: the
// compiler's DMA-alias waitcnt inserter can't see it (rule 18); lgkm waits
// are supplied manually, each followed by sched_barrier(0).
#define DSR(dst, base, imm)                                                 \
    asm volatile("ds_read_b128 %0, %1 offset:%2"                            \
        : "=v"(dst)                                                         \
        : "v"((const __attribute__((address_space(3))) bf16*)(base)),       \
          "i"(imm))

#define MF(i, j) acc[i][j] = __builtin_amdgcn_mfma_f32_16x16x32_bf16(       \
    af[i], bq[j], acc[i][j], 0, 0, 0);

// ============================================================================
// R10: m201-rhythm 256x256 GEMM (QKV & scores).
// 8 waves (2M x 4N), per-wave 128x64 (acc[8][4] -> AGPRs), BK=32,
// ring-4 LDS slots (A 16K + B 16K each = 128 KiB), 3-ahead prefetch.
// Per tile: 2 phases, each {ds_read burst (8/4) ; stage 1 half-tile (2) ;
// barrier ; lgkmcnt(0)+sched_barrier ; setprio(1) ; 16 MFMA ; setprio(0) ;
// barrier} -- the proven 8-phase rhythm (m201: 62% MfmaUtil at the same
// 2 waves/SIMD).  ONE counted vmcnt(8) per tile (never 0 mid-loop):
// entering tile t, tiles t+1,t+2 in flight (8 loads); stage t+3 (+4);
// vmcnt(8) -> t+1 landed.  Tail: vmcnt(4) -> vmcnt(0) -> bare.
// WAR: stage target slot (t+3)&3 was read at tile t-1; those reads drained
// by t-1's lgkm(0) before its final barrier; stage issues after it.
// LDS chunk-XOR swizzle (proven 0-conflict): slot q of row r holds global
// 16B chunk q ^ ((r>>1)&3); staging pre-swizzles the global source address.
// MODE_QKV:    C = bf16(acc + bias[col]);  MODE_SCORES: C = bf16(exp(a*acc))
// ============================================================================
template <int MODE, int NT>
__global__ __launch_bounds__(512) void mfma_nt256(
    const bf16* __restrict__ A, const bf16* __restrict__ B,
    const float* __restrict__ bias, void* __restrict__ Cv,
    int lda, int ldb, int ldc,
    long sA, long sB, long sC, float alpha)
{
    A += (long)blockIdx.z * sA;
    B += (long)blockIdx.z * sB;

    // 4 slots x (A 256x32 + B 256x32) = 4 x 8192 el x 2 = 128 KiB total
    __shared__ bf16 As[4 * 8192] __attribute__((aligned(16)));
    __shared__ bf16 Bs[4 * 8192] __attribute__((aligned(16)));

    const int t  = threadIdx.x;
    const int m0 = blockIdx.y * 256;
    const int n0 = blockIdx.x * 256;

    const int lane = t & 63;
    const int wave = t >> 6;
    const int wr   = (wave >> 2) * 128;  // wave row origin (M): 2 waves
    const int wc   = (wave & 3) * 64;    // wave col origin (N): 4 waves
    const int fr   = lane & 15;
    const int kq8  = lane >> 4;

    // staging decomposition (512 threads): A chunks c = t, t+512 (1024
    // chunks = 256 rows x 4); B same. chunk c -> row c>>2, slot c&3,
    // global k8-chunk = slot ^ ((row>>1)&3)
    const bf16* gA0; const bf16* gA1; const bf16* gB0; const bf16* gB1;
    {
        const int c0 = t,        r0 = c0 >> 2, h0 = ((c0 & 3) ^ ((r0 >> 1) & 3)) * 8;
        const int c1 = t + 512,  r1 = c1 >> 2, h1 = ((c1 & 3) ^ ((r1 >> 1) & 3)) * 8;
        gA0 = A + (long)(m0 + r0) * lda + h0;
        gA1 = A + (long)(m0 + r1) * lda + h1;
        gB0 = B + (long)(n0 + r0) * ldb + h0;
        gB1 = B + (long)(n0 + r1) * ldb + h1;
    }

    // fragment lane bases: addr = base + slot*16384B + frag*1024B (imms).
    // (r>>1)&3 == (fr>>1)&3 for every fragment row, so swz is lane-constant.
    const int swz = kq8 ^ ((fr >> 1) & 3);
    const bf16* pA = As + (wr + fr) * 32 + swz * 8;
    const bf16* pB = Bs + (wc + fr) * 32 + swz * 8;

    f32x4 acc[8][4] = {};
    bf16x8 af[8], bq[4];
    int kofs;

#define STA256(SS, ko)                                                      \
    gload_lds16(gA0 + (ko), &As[(SS) * 8192 + t * 8]);                      \
    gload_lds16(gA1 + (ko), &As[(SS) * 8192 + (t + 512) * 8]);
#define STB256(SS, ko)                                                      \
    gload_lds16(gB0 + (ko), &Bs[(SS) * 8192 + t * 8]);                      \
    gload_lds16(gB1 + (ko), &Bs[(SS) * 8192 + (t + 512) * 8]);

    // TB256(S, STG): one K-tile from slot S, two phases.
    //   STG=1 steady: stage A(t+3) in ph1, B(t+3) in ph2, end vmcnt(8)
    //   STG=3 tail-1: no stage, end vmcnt(4)
    //   STG=0 tail-2: no stage, end vmcnt(0)
    //   STG=2 last:   no stage, no wait, no trailing barrier
#define TB256(S, STG) do {                                                  \
    /* ---- phase 1: frags m0..3 + all B; MFMA upper half ---- */           \
    DSR(af[0], pA, (S) * 16384 + 0);                                        \
    DSR(af[1], pA, (S) * 16384 + 1024);                                     \
    DSR(af[2], pA, (S) * 16384 + 2048);                                     \
    DSR(af[3], pA, (S) * 16384 + 3072);                                     \
    DSR(bq[0], pB, (S) * 16384 + 0);                                        \
    DSR(bq[1], pB, (S) * 16384 + 1024);                                     \
    DSR(bq[2], pB, (S) * 16384 + 2048);                                     \
    DSR(bq[3], pB, (S) * 16384 + 3072);                                     \
    if constexpr ((STG) == 1) { STA256(((S) + 3) & 3, kofs); }              \
    __builtin_amdgcn_s_barrier();                                           \
    asm volatile("s_waitcnt lgkmcnt(0)" ::: "memory");                      \
    __builtin_amdgcn_sched_barrier(0);                                      \
    __builtin_amdgcn_s_setprio(1);                                          \
    MF(0,0) MF(0,1) MF(0,2) MF(0,3) MF(1,0) MF(1,1) MF(1,2) MF(1,3)         \
    MF(2,0) MF(2,1) MF(2,2) MF(2,3) MF(3,0) MF(3,1) MF(3,2) MF(3,3)         \
    __builtin_amdgcn_s_setprio(0);                                          \
    __builtin_amdgcn_s_barrier();                                           \
    /* ---- phase 2: frags m4..7; MFMA lower half ---- */                   \
    DSR(af[4], pA, (S) * 16384 + 4096);                                     \
    DSR(af[5], pA, (S) * 16384 + 5120);                                     \
    DSR(af[6], pA, (S) * 16384 + 6144);                                     \
    DSR(af[7], pA, (S) * 16384 + 7168);                                     \
    if constexpr ((STG) == 1) { STB256(((S) + 3) & 3, kofs); kofs += 32; }  \
    __builtin_amdgcn_s_barrier();                                           \
    asm volatile("s_waitcnt lgkmcnt(0)" ::: "memory");                      \
    __builtin_amdgcn_sched_barrier(0);                                      \
    __builtin_amdgcn_s_setprio(1);                                          \
    MF(4,0) MF(4,1) MF(4,2) MF(4,3) MF(5,0) MF(5,1) MF(5,2) MF(5,3)         \
    MF(6,0) MF(6,1) MF(6,2) MF(6,3) MF(7,0) MF(7,1) MF(7,2) MF(7,3)         \
    __builtin_amdgcn_s_setprio(0);                                          \
    if constexpr ((STG) == 1)                                               \
        asm volatile("s_waitcnt vmcnt(8)" ::: "memory");                    \
    else if constexpr ((STG) == 3)                                          \
        asm volatile("s_waitcnt vmcnt(4)" ::: "memory");                    \
    else if constexpr ((STG) == 0)                                          \
        asm volatile("s_waitcnt vmcnt(0)" ::: "memory");                    \
    if constexpr ((STG) != 2) __builtin_amdgcn_s_barrier();                 \
} while (0)

    // prologue: stage tiles 0,1,2 into slots 0,1,2; tile-0 landed
    STA256(0, 0);  STB256(0, 0);
    STA256(1, 32); STB256(1, 32);
    STA256(2, 64); STB256(2, 64);
    kofs = 96;
    asm volatile("s_waitcnt vmcnt(8)" ::: "memory");
    __builtin_amdgcn_s_barrier();

    static_assert(NT % 4 == 0 && NT >= 8, "ring-4 peel assumes NT%4==0");
    for (int g = 0; g < NT / 4 - 1; ++g) {           // tiles 0..NT-5 steady
        TB256(0, 1); TB256(1, 1); TB256(2, 1); TB256(3, 1);
    }
    TB256(0, 1);                                     // t=NT-4 (stages NT-1)
    TB256(1, 3); TB256(2, 0); TB256(3, 2);           // tail
#undef TB256
#undef STA256
#undef STB256

    // C/D layout: col=lane&15, row=(lane>>4)*4+reg  [m89-verified]
    const int r4 = (lane >> 4) * 4;
    bf16* C = (bf16*)Cv + (long)blockIdx.z * sC;
#pragma unroll
    for (int j = 0; j < 4; j++) {
        const int col = n0 + wc + j * 16 + fr;
        const float bv = (MODE == MODE_QKV) ? bias[col] : 0.f;
#pragma unroll
        for (int i = 0; i < 8; i++)
#pragma unroll
            for (int r = 0; r < 4; r++) {
                const long row = m0 + wr + i * 16 + r4 + r;
                float v = acc[i][j][r];
                if constexpr (MODE == MODE_QKV)
                    C[row * ldc + col] = (bf16)(v + bv);
                else
                    C[row * ldc + col] = (bf16)__expf(alpha * v);
            }
    }
}

// ============================================================================
// R9-proven 256x128 kernel (kept for PV, whose 128-block 256^2 grid would
// half-idle the machine). 8 waves (4M x 2N), ring-3, counted vmcnt(3).
// ============================================================================
template <int MODE, int NT>
__global__ __launch_bounds__(512) void mfma_nt(
    const bf16* __restrict__ A, const bf16* __restrict__ B,
    const float* __restrict__ bias, void* __restrict__ Cv,
    int lda, int ldb, int ldc,
    long sA, long sB, long sC, float alpha)
{
    A += (long)blockIdx.z * sA;
    B += (long)blockIdx.z * sB;

    __shared__ bf16 As[3 * 8192] __attribute__((aligned(16)));
    __shared__ bf16 Bs[3 * 4096] __attribute__((aligned(16)));

    const int t  = threadIdx.x;
    const int m0 = blockIdx.y * 256;
    const int n0 = blockIdx.x * 128;

    const int lane = t & 63;
    const int wave = t >> 6;
    const int wr   = (wave >> 1) * 64;
    const int wc   = (wave & 1) * 64;
    const int fr   = lane & 15;
    const int kq8  = lane >> 4;

    const bf16* gA0; const bf16* gA1; const bf16* gB0;
    {
        const int c0 = t,        r0 = c0 >> 2, h0 = ((c0 & 3) ^ ((r0 >> 1) & 3)) * 8;
        const int c1 = t + 512,  r1 = c1 >> 2, h1 = ((c1 & 3) ^ ((r1 >> 1) & 3)) * 8;
        gA0 = A + (long)(m0 + r0) * lda + h0;
        gA1 = A + (long)(m0 + r1) * lda + h1;
        gB0 = B + (long)(n0 + r0) * ldb + h0;
    }

    const int swz = kq8 ^ ((fr >> 1) & 3);
    const bf16* pA = As + (wr + fr) * 32 + swz * 8;
    const bf16* pB = Bs + (wc + fr) * 32 + swz * 8;

    f32x4 acc[4][4] = {};
    bf16x8 af[4], bq[4];
    int kofs;

#define STAGE3(SS, ko)                                                      \
    gload_lds16(gA0 + (ko), &As[(SS) * 8192 + t * 8]);                      \
    gload_lds16(gA1 + (ko), &As[(SS) * 8192 + (t + 512) * 8]);              \
    gload_lds16(gB0 + (ko), &Bs[(SS) * 4096 + t * 8]);

#define MF4(i, j) acc[i][j] = __builtin_amdgcn_mfma_f32_16x16x32_bf16(      \
    af[i], bq[j], acc[i][j], 0, 0, 0);

#define TB(CS, STG) do {                                                    \
    DSR(af[0], pA, (CS) * 16384 + 0);                                       \
    DSR(af[1], pA, (CS) * 16384 + 1024);                                    \
    DSR(bq[0], pB, (CS) * 8192 + 0);                                        \
    DSR(bq[1], pB, (CS) * 8192 + 1024);                                     \
    DSR(bq[2], pB, (CS) * 8192 + 2048);                                     \
    DSR(bq[3], pB, (CS) * 8192 + 3072);                                     \
    DSR(af[2], pA, (CS) * 16384 + 2048);                                    \
    DSR(af[3], pA, (CS) * 16384 + 3072);                                    \
    asm volatile("s_waitcnt lgkmcnt(2)" ::: "memory");                      \
    __builtin_amdgcn_sched_barrier(0);                                      \
    __builtin_amdgcn_s_setprio(1);                                          \
    MF4(0,0) MF4(0,1) MF4(1,0) MF4(1,1)                                     \
    MF4(0,2) MF4(0,3) MF4(1,2) MF4(1,3)                                     \
    __builtin_amdgcn_s_setprio(0);                                          \
    if constexpr ((STG) == 1) { STAGE3(((CS) + 2) % 3, kofs); kofs += 32; } \
    asm volatile("s_waitcnt lgkmcnt(0)" ::: "memory");                      \
    __builtin_amdgcn_sched_barrier(0);                                      \
    __builtin_amdgcn_s_setprio(1);                                          \
    MF4(2,0) MF4(2,1) MF4(3,0) MF4(3,1)                                     \
    MF4(2,2) MF4(2,3) MF4(3,2) MF4(3,3)                                     \
    __builtin_amdgcn_s_setprio(0);                                          \
    if constexpr ((STG) == 1)                                               \
        asm volatile("s_waitcnt vmcnt(3)" ::: "memory");                    \
    else if constexpr ((STG) == 0)                                          \
        asm volatile("s_waitcnt vmcnt(0)" ::: "memory");                    \
    if constexpr ((STG) != 2) __builtin_amdgcn_s_barrier();                 \
} while (0)

    STAGE3(0, 0);
    STAGE3(1, 32);
    kofs = 64;
    asm volatile("s_waitcnt vmcnt(3)" ::: "memory");
    __builtin_amdgcn_s_barrier();

    static_assert(NT % 3 != 0, "peel pattern assumes NT%3 in {1,2}");
    if constexpr (NT % 3 == 2) {
        TB(0, 1); TB(1, 1);
        for (int g = 0; g < (NT - 5) / 3; ++g) { TB(2, 1); TB(0, 1); TB(1, 1); }
        TB(2, 1); TB(0, 0); TB(1, 2);
    } else {
        TB(0, 1);
        for (int g = 0; g < (NT - 4) / 3; ++g) { TB(1, 1); TB(2, 1); TB(0, 1); }
        TB(1, 1); TB(2, 0); TB(0, 2);
    }
#undef TB
#undef STAGE3
#undef MF4

    const int r4 = (lane >> 4) * 4;
    if constexpr (MODE == MODE_PV) {
        float* C = (float*)Cv + (long)blockIdx.z * sC;
#pragma unroll
        for (int j = 0; j < 4; j++) {
            const int col = n0 + wc + j * 16 + fr;
#pragma unroll
            for (int i = 0; i < 4; i++)
#pragma unroll
                for (int r = 0; r < 4; r++) {
                    const long row = m0 + wr + i * 16 + r4 + r;
                    C[row * ldc + col] = acc[i][j][r];
                }
        }
    } else {
        bf16* C = (bf16*)Cv + (long)blockIdx.z * sC;
#pragma unroll
        for (int j = 0; j < 4; j++) {
            const int col = n0 + wc + j * 16 + fr;
            const float bv = (MODE == MODE_QKV) ? bias[col] : 0.f;
#pragma unroll
            for (int i = 0; i < 4; i++)
#pragma unroll
                for (int r = 0; r < 4; r++) {
                    const long row = m0 + wr + i * 16 + r4 + r;
                    float v = acc[i][j][r];
                    if constexpr (MODE == MODE_QKV)
                        C[row * ldc + col] = (bf16)(v + bv);
                    else
                        C[row * ldc + col] = (bf16)__expf(alpha * v);
                }
        }
    }
}

__global__ __launch_bounds__(256) void f32_to_bf16(
    const float* __restrict__ in, bf16* __restrict__ out, long n)
{
    long i = ((long)blockIdx.x * 256 + threadIdx.x) * 4;
    if (i < n) {
        float4 v = *(const float4*)(in + i);
        bf16x4 o = { (bf16)v.x, (bf16)v.y, (bf16)v.z, (bf16)v.w };
        *(bf16x4*)(out + i) = o;
    }
}

// Vt[b][e][s] = V[b][s][e]; V has ld 3072 (inside qkv), Vt ld 2048.
__global__ __launch_bounds__(256) void transpose_v(
    const bf16* __restrict__ V, bf16* __restrict__ Vt)
{
    __shared__ bf16 tile[32][33];
    const bf16* Vb  = V  + (long)blockIdx.z * 2048 * 3072;
    bf16*       Vtb = Vt + (long)blockIdx.z * 1024 * 2048;
    const int s0 = blockIdx.x * 32, e0 = blockIdx.y * 32;
    const int tx = threadIdx.x & 31, ty = threadIdx.x >> 5;
#pragma unroll
    for (int i = 0; i < 32; i += 8)
        tile[ty + i][tx] = Vb[(long)(s0 + ty + i) * 3072 + e0 + tx];
    __syncthreads();
#pragma unroll
    for (int i = 0; i < 32; i += 8)
        Vtb[(long)(e0 + ty + i) * 2048 + s0 + tx] = tile[tx][ty + i];
}

// Per row: sum exp-scores, write fp32 out1 = Pu/l, renormalize Pu IN PLACE (bf16).
__global__ __launch_bounds__(256) void norm_rows(
    bf16* __restrict__ Pu, float* __restrict__ out1)
{
    bf16* p  = Pu   + (long)blockIdx.x * 2048;
    float* o = out1 + (long)blockIdx.x * 2048;
    const int t = threadIdx.x;
    bf16x8 v = *(const bf16x8*)(p + t * 8);
    float f[8];
    float s = 0.f;
#pragma unroll
    for (int k = 0; k < 8; k++) { f[k] = (float)v[k]; s += f[k]; }
#pragma unroll
    for (int off = 32; off > 0; off >>= 1) s += __shfl_xor(s, off);
    __shared__ float red[4];
    const int wid = t >> 6, lane = t & 63;
    if (lane == 0) red[wid] = s;
    __syncthreads();
    s = red[0] + red[1] + red[2] + red[3];
    const float inv = 1.0f / s;
    float4 a, b;
    a.x = f[0] * inv; a.y = f[1] * inv; a.z = f[2] * inv; a.w = f[3] * inv;
    b.x = f[4] * inv; b.y = f[5] * inv; b.z = f[6] * inv; b.w = f[7] * inv;
    *(float4*)(o + t * 8)     = a;
    *(float4*)(o + t * 8 + 4) = b;
    bf16x8 w;
#pragma unroll
    for (int k = 0; k < 8; k++) w[k] = (bf16)(f[k] * inv);
    *(bf16x8*)(p + t * 8) = w;
}

extern "C" void kernel_launch(void* const* d_in, const int* in_sizes, int n_in,
                              void* d_out, int out_size, void* d_ws, size_t ws_size,
                              hipStream_t stream)
{
    const int B = 4, S = 2048, E = 1024;
    const float* X    = (const float*)d_in[0];   // [B,S,E]
    const float* W    = (const float*)d_in[1];   // [3E,E]
    const float* bias = (const float*)d_in[2];   // [3E]

    float* out0 = (float*)d_out;                  // [B,S,E]
    float* out1 = out0 + (long)B * S * E;         // [B,S,S]

    // ws layout (bytes):
    //   [ 0M, 48M)  qkvb bf16 [B*S, 3072]
    //   [48M, 64M)  Vt   bf16 [B][E][S]
    //   [64M, 96M)  Pu   bf16 [B][S][S]  (exp-scores; renormalized in place)
    //   Xb [64M,80M) and Wb [80M,86.3M) overlap Pu — dead before Pu is written.
    char* ws = (char*)d_ws;
    bf16* qkvb = (bf16*)(ws);
    bf16* Vt   = (bf16*)(ws + 50331648);
    bf16* Pu   = (bf16*)(ws + 67108864);
    bf16* Xb   = (bf16*)(ws + 67108864);
    bf16* Wb   = (bf16*)(ws + 83886080);

    f32_to_bf16<<<(long)B * S * E / 1024, 256, 0, stream>>>(X, Xb, (long)B * S * E);
    f32_to_bf16<<<(long)3 * E * E / 1024, 256, 0, stream>>>(W, Wb, (long)3 * E * E);

    // qkvb = bf16(X @ W^T + b)   [M=8192, N=3072, K=1024] -> 12x32 = 384 blocks
    mfma_nt256<MODE_QKV, 32><<<dim3(3 * E / 256, B * S / 256, 1), 512, 0, stream>>>(
        Xb, Wb, bias, qkvb, E, E, 3 * E, 0, 0, 0, 1.0f);

    // Vt = V^T per batch
    transpose_v<<<dim3(S / 32, E / 32, B), 256, 0, stream>>>(qkvb + 2 * E, Vt);

    // Pu = bf16(exp(Q @ K^T / 32))  [2048x2048, K=1024] x4 -> 256 blocks
    mfma_nt256<MODE_SCORES, 32><<<dim3(S / 256, S / 256, B), 512, 0, stream>>>(
        qkvb, qkvb + E, nullptr, Pu, 3 * E, 3 * E, S,
        (long)S * 3 * E, (long)S * 3 * E, (long)S * S, 0.03125f);

    // out1 = Pu / rowsum  (fp32); Pu <- normalized bf16 in place
    norm_rows<<<B * S, 256, 0, stream>>>(Pu, out1);

    // out0 = P @ V  (= Pu @ Vt^T, NT)  [2048x1024, K=2048] x4 -> 256 blocks
    mfma_nt<MODE_PV, 64><<<dim3(E / 128, S / 256, B), 512, 0, stream>>>(
        Pu, Vt, nullptr, out0, S, S, E,
        (long)S * S, (long)E * S, (long)S * E, 1.0f);
}

// Round 11
// 283.422 us; speedup vs baseline: 1.1194x; 1.1194x over previous
//
#include <hip/hip_runtime.h>
#include <math.h>

typedef __bf16 bf16;
typedef __bf16 bf16x4 __attribute__((ext_vector_type(4)));
typedef __bf16 bf16x8 __attribute__((ext_vector_type(8)));
typedef float f32x4 __attribute__((ext_vector_type(4)));

#define MODE_QKV    0
#define MODE_SCORES 1
#define MODE_PV     2

__device__ inline void gload_lds16(const bf16* g, bf16* l) {
    __builtin_amdgcn_global_load_lds(
        (const __attribute__((address_space(1))) void*)g,
        (__attribute__((address_space(3))) void*)l, 16, 0, 0);
}

// ds_read_b128 with a compile-time immediate offset. asm-opaque: the
// compiler's DMA-alias waitcnt inserter can't see it (rule 18); lgkm waits
// are supplied manually, each followed by sched_barrier(0).
#define DSR(dst, base, imm)                                                 \
    asm volatile("ds_read_b128 %0, %1 offset:%2"                            \
        : "=v"(dst)                                                         \
        : "v"((const __attribute__((address_space(3))) bf16*)(base)),       \
          "i"(imm))

#define MF(i, j) acc[i][j] = __builtin_amdgcn_mfma_f32_16x16x32_bf16(       \
    af[i], bq[j], acc[i][j], 0, 0, 0);

// NT GEMM, 256x128 tile, BK=32, 8 waves (4M x 2N), 512 threads, per-wave
// 64x64 output, MFMA 16x16x32, 3-slot LDS ring, 2-ahead prefetch, counted
// vmcnt(3).  R9-proven K-loop (best measured config; R10's 256^2 8-phase
// port regressed to 25% MfmaUtil at 1 block/CU -- deep-schedule ports are
// a co-designed combo, not graftable).  R11 touches ONLY epilogues:
//   MODE_QKV:    n0 <  2048 -> C(ld 2048) = bf16(acc + bias[col])  [Q|K]
//                n0 >= 2048 -> write V DIRECTLY TRANSPOSED to Vt[b][e][s]
//                (kills the transpose_v kernel + V region of qkvb)
//   MODE_SCORES: C = bf16(exp(alpha*acc))  (unnormalized exp-scores)
//   MODE_PV:     C = fp32 acc * inv[row]   (inv from norm_rows via `bias`;
//                kills the Pu in-place renormalize; R7 lesson: NO atomics)
template <int MODE, int NT>
__global__ __launch_bounds__(512) void mfma_nt(
    const bf16* __restrict__ A, const bf16* __restrict__ B,
    const float* __restrict__ bias, void* __restrict__ Cv,
    bf16* __restrict__ Vtp,
    int lda, int ldb, int ldc,
    long sA, long sB, long sC, float alpha)
{
    A += (long)blockIdx.z * sA;
    B += (long)blockIdx.z * sB;

    // 3 slots: A 256x32 (8192 el = 16 KiB), B 128x32 (4096 el = 8 KiB)
    __shared__ bf16 As[3 * 8192] __attribute__((aligned(16)));
    __shared__ bf16 Bs[3 * 4096] __attribute__((aligned(16)));

    const int t  = threadIdx.x;
    const int m0 = blockIdx.y * 256;
    const int n0 = blockIdx.x * 128;

    const int lane = t & 63;
    const int wave = t >> 6;
    const int wr   = (wave >> 1) * 64;   // wave row origin (M): 4 waves
    const int wc   = (wave & 1) * 64;    // wave col origin (N): 2 waves
    const int fr   = lane & 15;
    const int kq8  = lane >> 4;

    // staging decomposition (512 threads): A chunks c = t, t+512; B c = t.
    // chunk c -> row c>>2, slot c&3, global k8-chunk = slot ^ ((row>>1)&3)
    const bf16* gA0; const bf16* gA1; const bf16* gB0;
    {
        const int c0 = t,        r0 = c0 >> 2, h0 = ((c0 & 3) ^ ((r0 >> 1) & 3)) * 8;
        const int c1 = t + 512,  r1 = c1 >> 2, h1 = ((c1 & 3) ^ ((r1 >> 1) & 3)) * 8;
        gA0 = A + (long)(m0 + r0) * lda + h0;
        gA1 = A + (long)(m0 + r1) * lda + h1;
        gB0 = B + (long)(n0 + r0) * ldb + h0;
    }

    // fragment lane bases: addr = base + slot*SZ + frag*1024B (immediates).
    // (r>>1)&3 == (fr>>1)&3 for every fragment row, so swz is lane-constant.
    const int swz = kq8 ^ ((fr >> 1) & 3);
    const bf16* pA = As + (wr + fr) * 32 + swz * 8;
    const bf16* pB = Bs + (wc + fr) * 32 + swz * 8;

    f32x4 acc[4][4] = {};
    bf16x8 af[4], bq[4];
    int kofs;

#define STAGE3(SS, ko)                                                      \
    gload_lds16(gA0 + (ko), &As[(SS) * 8192 + t * 8]);                      \
    gload_lds16(gA1 + (ko), &As[(SS) * 8192 + (t + 512) * 8]);              \
    gload_lds16(gB0 + (ko), &Bs[(SS) * 4096 + t * 8]);

    // TB(CS, STG): one K-tile from slot CS.
    //   STG=1: stage tile t+2 into slot (CS+2)%3, end with vmcnt(3)+barrier
    //   STG=0: no stage, end with vmcnt(0)+barrier
    //   STG=2: last tile: no stage, no wait, no barrier
#define TB(CS, STG) do {                                                    \
    DSR(af[0], pA, (CS) * 16384 + 0);                                       \
    DSR(af[1], pA, (CS) * 16384 + 1024);                                    \
    DSR(bq[0], pB, (CS) * 8192 + 0);                                        \
    DSR(bq[1], pB, (CS) * 8192 + 1024);                                     \
    DSR(bq[2], pB, (CS) * 8192 + 2048);                                     \
    DSR(bq[3], pB, (CS) * 8192 + 3072);                                     \
    DSR(af[2], pA, (CS) * 16384 + 2048);                                    \
    DSR(af[3], pA, (CS) * 16384 + 3072);                                    \
    asm volatile("s_waitcnt lgkmcnt(2)" ::: "memory");                      \
    __builtin_amdgcn_sched_barrier(0);                                      \
    __builtin_amdgcn_s_setprio(1);                                          \
    MF(0,0) MF(0,1) MF(1,0) MF(1,1)                                         \
    MF(0,2) MF(0,3) MF(1,2) MF(1,3)                                         \
    __builtin_amdgcn_s_setprio(0);                                          \
    if constexpr ((STG) == 1) { STAGE3(((CS) + 2) % 3, kofs); kofs += 32; } \
    asm volatile("s_waitcnt lgkmcnt(0)" ::: "memory");                      \
    __builtin_amdgcn_sched_barrier(0);                                      \
    __builtin_amdgcn_s_setprio(1);                                          \
    MF(2,0) MF(2,1) MF(3,0) MF(3,1)                                         \
    MF(2,2) MF(2,3) MF(3,2) MF(3,3)                                         \
    __builtin_amdgcn_s_setprio(0);                                          \
    if constexpr ((STG) == 1)                                               \
        asm volatile("s_waitcnt vmcnt(3)" ::: "memory");                    \
    else if constexpr ((STG) == 0)                                          \
        asm volatile("s_waitcnt vmcnt(0)" ::: "memory");                    \
    if constexpr ((STG) != 2) __builtin_amdgcn_s_barrier();                 \
} while (0)

    // prologue: stage tiles 0 (slot 0) and 1 (slot 1); tile-0 landed
    STAGE3(0, 0);
    STAGE3(1, 32);
    kofs = 64;
    asm volatile("s_waitcnt vmcnt(3)" ::: "memory");
    __builtin_amdgcn_s_barrier();

    static_assert(NT % 3 != 0, "peel pattern assumes NT%3 in {1,2}");
    if constexpr (NT % 3 == 2) {
        TB(0, 1); TB(1, 1);
        for (int g = 0; g < (NT - 5) / 3; ++g) { TB(2, 1); TB(0, 1); TB(1, 1); }
        TB(2, 1); TB(0, 0); TB(1, 2);
    } else {
        TB(0, 1);
        for (int g = 0; g < (NT - 4) / 3; ++g) { TB(1, 1); TB(2, 1); TB(0, 1); }
        TB(1, 1); TB(2, 0); TB(0, 2);
    }
#undef TB
#undef STAGE3

    // C/D layout: col=lane&15, row=(lane>>4)*4+reg  [m89-verified]
    const int r4 = (lane >> 4) * 4;
    if constexpr (MODE == MODE_PV) {
        float* C = (float*)Cv + (long)blockIdx.z * sC;
        const float* Rs = bias + (long)blockIdx.z * 2048;   // 1/rowsum
        float iv[4][4];
#pragma unroll
        for (int i = 0; i < 4; i++)
#pragma unroll
            for (int r = 0; r < 4; r++)
                iv[i][r] = Rs[m0 + wr + i * 16 + r4 + r];
#pragma unroll
        for (int j = 0; j < 4; j++) {
            const int col = n0 + wc + j * 16 + fr;
#pragma unroll
            for (int i = 0; i < 4; i++)
#pragma unroll
                for (int r = 0; r < 4; r++) {
                    const long row = m0 + wr + i * 16 + r4 + r;
                    C[row * ldc + col] = acc[i][j][r] * iv[i][r];
                }
        }
    } else if constexpr (MODE == MODE_QKV) {
        if (n0 >= 2048) {
            // V block: write transposed straight to Vt[b][e][s] (bf16x4
            // along s; r4 is a multiple of 4 -> 8B-aligned)
            const int  bi = m0 >> 11;
            bf16* Vb = Vtp + (long)bi * (1024 * 2048);
#pragma unroll
            for (int j = 0; j < 4; j++) {
                const int col = n0 + wc + j * 16 + fr;
                const int e   = col - 2048;
                const float bv = bias[col];
#pragma unroll
                for (int i = 0; i < 4; i++) {
                    const int sb = (m0 + wr + i * 16 + r4) & 2047;
                    bf16x4 o = { (bf16)(acc[i][j][0] + bv),
                                 (bf16)(acc[i][j][1] + bv),
                                 (bf16)(acc[i][j][2] + bv),
                                 (bf16)(acc[i][j][3] + bv) };
                    *(bf16x4*)&Vb[(long)e * 2048 + sb] = o;
                }
            }
        } else {
            bf16* C = (bf16*)Cv;
#pragma unroll
            for (int j = 0; j < 4; j++) {
                const int col = n0 + wc + j * 16 + fr;
                const float bv = bias[col];
#pragma unroll
                for (int i = 0; i < 4; i++)
#pragma unroll
                    for (int r = 0; r < 4; r++) {
                        const long row = m0 + wr + i * 16 + r4 + r;
                        C[row * ldc + col] = (bf16)(acc[i][j][r] + bv);
                    }
            }
        }
    } else {
        bf16* C = (bf16*)Cv + (long)blockIdx.z * sC;
#pragma unroll
        for (int j = 0; j < 4; j++) {
            const int col = n0 + wc + j * 16 + fr;
#pragma unroll
            for (int i = 0; i < 4; i++)
#pragma unroll
                for (int r = 0; r < 4; r++) {
                    const long row = m0 + wr + i * 16 + r4 + r;
                    C[row * ldc + col] = (bf16)__expf(alpha * acc[i][j][r]);
                }
        }
    }
}

// merged f32->bf16 for X then W in one launch (saves a launch gap)
__global__ __launch_bounds__(256) void f32_to_bf16_2(
    const float* __restrict__ X, bf16* __restrict__ Xb, long nX,
    const float* __restrict__ W, bf16* __restrict__ Wb, long nW)
{
    long i = ((long)blockIdx.x * 256 + threadIdx.x) * 4;
    const float* in; bf16* out; long idx;
    if (i < nX) { in = X; out = Xb; idx = i; }
    else        { in = W; out = Wb; idx = i - nX; if (idx >= nW) return; }
    float4 v = *(const float4*)(in + idx);
    bf16x4 o = { (bf16)v.x, (bf16)v.y, (bf16)v.z, (bf16)v.w };
    *(bf16x4*)(out + idx) = o;
}

// Per row: sum exp-scores, write fp32 out1 = Pu/l and rs[row] = 1/l.
// (Pu itself is NOT rewritten; PV scales by rs instead. -32MB HBM.)
__global__ __launch_bounds__(256) void norm_rows(
    const bf16* __restrict__ Pu, float* __restrict__ out1,
    float* __restrict__ rs)
{
    const bf16* p = Pu  + (long)blockIdx.x * 2048;
    float* o = out1 + (long)blockIdx.x * 2048;
    const int t = threadIdx.x;
    bf16x8 v = *(const bf16x8*)(p + t * 8);
    float f[8];
    float s = 0.f;
#pragma unroll
    for (int k = 0; k < 8; k++) { f[k] = (float)v[k]; s += f[k]; }
#pragma unroll
    for (int off = 32; off > 0; off >>= 1) s += __shfl_xor(s, off);
    __shared__ float red[4];
    const int wid = t >> 6, lane = t & 63;
    if (lane == 0) red[wid] = s;
    __syncthreads();
    s = red[0] + red[1] + red[2] + red[3];
    const float inv = 1.0f / s;
    if (t == 0) rs[blockIdx.x] = inv;
    float4 a, b;
    a.x = f[0] * inv; a.y = f[1] * inv; a.z = f[2] * inv; a.w = f[3] * inv;
    b.x = f[4] * inv; b.y = f[5] * inv; b.z = f[6] * inv; b.w = f[7] * inv;
    *(float4*)(o + t * 8)     = a;
    *(float4*)(o + t * 8 + 4) = b;
}

extern "C" void kernel_launch(void* const* d_in, const int* in_sizes, int n_in,
                              void* d_out, int out_size, void* d_ws, size_t ws_size,
                              hipStream_t stream)
{
    const int B = 4, S = 2048, E = 1024;
    const float* X    = (const float*)d_in[0];   // [B,S,E]
    const float* W    = (const float*)d_in[1];   // [3E,E]
    const float* bias = (const float*)d_in[2];   // [3E]

    float* out0 = (float*)d_out;                  // [B,S,E]
    float* out1 = out0 + (long)B * S * E;         // [B,S,S]

    // ws layout (bytes):
    //   [ 0M, 32M)  qkvb bf16 [B*S, 2048]  (Q|K only; V goes straight to Vt)
    //   [32M, 48M)  Vt   bf16 [B][E][S]
    //   [48M, 48M+32K) rs fp32 [B*S]  (1/rowsum)
    //   [64M, 96M)  Pu   bf16 [B][S][S]  (unnormalized exp-scores)
    //   Xb [64M,80M) and Wb [80M,86M) overlap Pu — dead before Pu is written.
    char* ws = (char*)d_ws;
    bf16*  qkvb = (bf16*)(ws);
    bf16*  Vt   = (bf16*)(ws + 33554432);
    float* rs   = (float*)(ws + 50331648);
    bf16*  Pu   = (bf16*)(ws + 67108864);
    bf16*  Xb   = (bf16*)(ws + 67108864);
    bf16*  Wb   = (bf16*)(ws + 83886080);

    const long nX = (long)B * S * E;      // 8,388,608
    const long nW = (long)3 * E * E;      // 3,145,728
    f32_to_bf16_2<<<(nX + nW) / 1024, 256, 0, stream>>>(X, Xb, nX, W, Wb, nW);

    // qkvb = bf16(X @ W^T + b) for Q|K (ldc 2048); V written transposed to Vt
    // [M=8192, N=3072, K=1024] -> 24x32 = 768 blocks
    mfma_nt<MODE_QKV, 32><<<dim3(3 * E / 128, B * S / 256, 1), 512, 0, stream>>>(
        Xb, Wb, bias, qkvb, Vt, E, E, 2048, 0, 0, 0, 1.0f);

    // Pu = bf16(exp(Q @ K^T / 32))  [2048x2048, K=1024] x4 -> 512 blocks
    mfma_nt<MODE_SCORES, 32><<<dim3(S / 128, S / 256, B), 512, 0, stream>>>(
        qkvb, qkvb + 1024, nullptr, Pu, nullptr, 2048, 2048, S,
        (long)S * 2048, (long)S * 2048, (long)S * S, 0.03125f);

    // out1 = Pu / rowsum (fp32); rs = 1/rowsum (Pu untouched)
    norm_rows<<<B * S, 256, 0, stream>>>(Pu, out1, rs);

    // out0 = (Pu @ Vt^T) * rs[row]  [2048x1024, K=2048] x4 -> 256 blocks
    mfma_nt<MODE_PV, 64><<<dim3(E / 128, S / 256, B), 512, 0, stream>>>(
        Pu, Vt, rs, out0, nullptr, S, S, E,
        (long)S * S, (long)E * S, (long)S * E, 1.0f);
}